// Round 11
// baseline (1272.888 us; speedup 1.0000x reference)
//
#include <hip/hip_runtime.h>
#include <math.h>

#define TT 2048
#define UU 64
#define NBLK 128   // 2 batch elements per block
#define NTHR 384   // 6 waves: 2 x {prod-(i,j), prod-(f,o), consumer}

typedef float v2f __attribute__((ext_vector_type(2)));
typedef float v4f __attribute__((ext_vector_type(4)));

// Fast activations on v_exp_f32 / v_rcp_f32 (~1e-7 abs err; threshold 3.45e-6;
// validated at absmax 9.5e-7 in rounds 0-10).
__device__ __forceinline__ float frcp(float x) { return __builtin_amdgcn_rcpf(x); }
__device__ __forceinline__ float fsigmoid(float x) { return frcp(1.0f + __expf(-x)); }
__device__ __forceinline__ float ftanh(float x) { return 1.0f - 2.0f * frcp(1.0f + __expf(2.0f * x)); }

// VOP3P op_sel splat-FMA (r10-validated): both halves of the result consume
// the SAME 32-bit half of h -- the (h,h) splat is never materialized.
__device__ __forceinline__ void pkfma_ll(v2f& a, v2f h, v2f w) {
    asm("v_pk_fma_f32 %0, %1, %2, %0 op_sel:[0,0,0] op_sel_hi:[0,1,1]"
        : "+v"(a) : "v"(h), "v"(w));
}
__device__ __forceinline__ void pkfma_hh(v2f& a, v2f h, v2f w) {
    asm("v_pk_fma_f32 %0, %1, %2, %0 op_sel:[1,0,0] op_sel_hi:[1,1,1]"
        : "+v"(a) : "v"(h), "v"(w));
}

// ROUND-10 POST-MORTEM: 999us (prediction matched; op_sel splat + reg-z cuts
// real). Remaining step = ~1170cy with only ~320cy VALU -> stall-dominated,
// and each wave sits ALONE on its SIMD (3 waves, 4 SIMDs, 1 block/CU): every
// stall is a dead cycle. THIS ROUND: occupancy of the stall windows -- TWO
// independent batch elements per block (grid 128, 6 waves). Wave->SIMD
// round-robin co-locates waves of DIFFERENT recurrences on a SIMD, so one
// recurrence's LDS/act stalls are filled by the other's issue. Per-SIMD
// issue ~640cy < step ~1170cy -> step time ~unchanged, throughput ~2x.
// Per-wave code is byte-identical to r10 -> bit-identical numerics.
//
// Waves 0..2 serve element A (= 2*blockIdx), waves 3..5 element B (+1):
//   wl=0: producer gates (i,j); wl=1: producer gates (f,o); wl=2: consumer.
// Protocol per element exactly r10's: matvec (16 uniform b128 h reads + 64
// op_sel pkfma), write own z pair, ONE shared barrier, read other pair,
// redundant (c0,h) update, write private plain-h ring. Consumer reads its
// element's wave0-ring one step lagged (written in (B(t),B(t+1)), rewritten
// after B(t+2): race-free). All 6 waves execute exactly 1 + TT + 1 barriers.
__global__
__attribute__((amdgpu_flat_work_group_size(NTHR, NTHR)))
__attribute__((amdgpu_waves_per_eu(2, 2)))
void lstm_ts_kernel(
    const float* __restrict__ x, const float* __restrict__ W0,
    const float* __restrict__ b0, const float* __restrict__ W1,
    const float* __restrict__ b1, const float* __restrict__ Wd,
    const float* __restrict__ bd, float* __restrict__ out)
{
    __shared__ __align__(16) float xbuf[2][TT];        // 16 KB
    __shared__ __align__(16) float ringS0[2][2][UU];   // [eid][slot][u]
    __shared__ __align__(16) float ringS1[2][2][UU];
    __shared__ __align__(16) v2f zb0[2][UU];           // [eid][u] (z_i,z_j)
    __shared__ __align__(16) v2f zb1[2][UU];           // [eid][u] (z_f,z_o)
    __shared__ float red[2][3];

    const int tid = threadIdx.x;
    const int wid = tid >> 6;
    const int u = tid & 63;
    const int eid = (wid >= 3) ? 1 : 0;   // which batch element this wave serves
    const int wl = wid - 3 * eid;         // role within the element group
    const int b = 2 * blockIdx.x + eid;
    const float* xrow = x + b * TT;
    float* outrow = out + b * TT;

    // ---- prologue: each 3-wave group stages its own element's x ----
    float ss = 0.f;
    const int ltid = wl * 64 + u;  // 0..191 within the group
    for (int i = ltid; i < TT; i += 192) {
        float v = xrow[i];
        xbuf[eid][i] = v;
        ss += v * v;
    }
    #pragma unroll
    for (int m = 1; m < 64; m <<= 1) ss += __shfl_xor(ss, m, 64);
    if (u == 0) red[eid][wl] = ss;
    if (wl < 2) {  // h_{-1} = 0: step 0 reads slot 1
        (wl == 0 ? ringS0 : ringS1)[eid][1][u] = 0.f;
    }
    __syncthreads();  // B0

    if (wl < 2) {
        // ============ PRODUCER wave 'wl' of element eid ============
        const int go = wl * 128;  // column offset: 0 -> (i,j), 128 -> (f,o)
        const float sq = (red[eid][0] + red[eid][1]) + red[eid][2];
        const float scale = 1.0f / sqrtf(fmaxf(sq, 1e-12f));  // precise, once

        // 64 named v2f = 128 weight VGPRs (identical to r10).
        #define DECLW(k) v2f WP##k; { const float* r_ = W0 + (1 + (k)) * 256 + go; \
            WP##k.x = r_[u]; WP##k.y = r_[64 + u]; } \
            asm volatile("" : "+v"(WP##k));
        DECLW(0)  DECLW(1)  DECLW(2)  DECLW(3)  DECLW(4)  DECLW(5)  DECLW(6)  DECLW(7)
        DECLW(8)  DECLW(9)  DECLW(10) DECLW(11) DECLW(12) DECLW(13) DECLW(14) DECLW(15)
        DECLW(16) DECLW(17) DECLW(18) DECLW(19) DECLW(20) DECLW(21) DECLW(22) DECLW(23)
        DECLW(24) DECLW(25) DECLW(26) DECLW(27) DECLW(28) DECLW(29) DECLW(30) DECLW(31)
        DECLW(32) DECLW(33) DECLW(34) DECLW(35) DECLW(36) DECLW(37) DECLW(38) DECLW(39)
        DECLW(40) DECLW(41) DECLW(42) DECLW(43) DECLW(44) DECLW(45) DECLW(46) DECLW(47)
        DECLW(48) DECLW(49) DECLW(50) DECLW(51) DECLW(52) DECLW(53) DECLW(54) DECLW(55)
        DECLW(56) DECLW(57) DECLW(58) DECLW(59) DECLW(60) DECLW(61) DECLW(62) DECLW(63)
        #undef DECLW

        const float wxa = W0[go + u] * scale;       // x-weight, gate a (i or f)
        const float wxb = W0[go + 64 + u] * scale;  // gate b (j or o)
        const float bca = b0[go + u], bcb = b0[go + 64 + u];

        float (*myring)[UU] = (wl == 0) ? ringS0[eid] : ringS1[eid];
        v2f* zbme = (wl == 0) ? zb0[eid] : zb1[eid];
        v2f* zbot = (wl == 0) ? zb1[eid] : zb0[eid];

        float c0 = 0.f;

        for (int t = 0; t < TT; ++t) {
            const float xr = xbuf[eid][t];          // uniform broadcast
            const float* hs = myring[(t + 1) & 1];  // h_{t-1} (own private copy)

            // 4 chains x 16 deep; x-term folded into chain 0 (r10 bit-identical)
            v2f a0, a1 = 0.f, a2 = 0.f, a3 = 0.f;
            a0.x = fmaf(xr, wxa, bca); a0.y = fmaf(xr, wxb, bcb);

            // ONE uniform b128 read = h_{4m..4m+3} -> 4 op_sel pkfma
            #define MAC4(m, Wa, Wb, Wc, Wd_) { \
                v4f hv_ = *(const v4f*)(hs + 4 * (m)); \
                v2f h01_ = __builtin_shufflevector(hv_, hv_, 0, 1); \
                v2f h23_ = __builtin_shufflevector(hv_, hv_, 2, 3); \
                pkfma_ll(a0, h01_, Wa); pkfma_hh(a1, h01_, Wb); \
                pkfma_ll(a2, h23_, Wc); pkfma_hh(a3, h23_, Wd_); \
            }
            MAC4(0,  WP0,  WP1,  WP2,  WP3)
            MAC4(1,  WP4,  WP5,  WP6,  WP7)
            MAC4(2,  WP8,  WP9,  WP10, WP11)
            MAC4(3,  WP12, WP13, WP14, WP15)
            MAC4(4,  WP16, WP17, WP18, WP19)
            MAC4(5,  WP20, WP21, WP22, WP23)
            MAC4(6,  WP24, WP25, WP26, WP27)
            MAC4(7,  WP28, WP29, WP30, WP31)
            MAC4(8,  WP32, WP33, WP34, WP35)
            MAC4(9,  WP36, WP37, WP38, WP39)
            MAC4(10, WP40, WP41, WP42, WP43)
            MAC4(11, WP44, WP45, WP46, WP47)
            MAC4(12, WP48, WP49, WP50, WP51)
            MAC4(13, WP52, WP53, WP54, WP55)
            MAC4(14, WP56, WP57, WP58, WP59)
            MAC4(15, WP60, WP61, WP62, WP63)
            #undef MAC4

            const v2f zown = (a0 + a1) + (a2 + a3);  // own (zA, zB) pair
            zbme[u] = zown;                          // ds_write_b64
            __syncthreads();                         // B(t+1): pairs exchanged

            const v2f zoth = zbot[u];                // only the OTHER pair
            const v2f zij = (wl == 0) ? zown : zoth;
            const v2f zfo = (wl == 0) ? zoth : zown;

            // redundant unit update -- bit-identical in both producer waves
            c0 = fsigmoid(zfo.x + 1.0f) * c0 + fsigmoid(zij.x) * ftanh(zij.y);
            const float h = fsigmoid(zfo.y) * ftanh(c0);

            myring[t & 1][u] = h;  // plain h ring, b32 write
        }
        __syncthreads();  // B(TT+1)
    } else {
        // ======== CONSUMER of element eid: layer 1 + dense + store ========
        const float w1v0 = W1[u * 4 + 0], w1v1 = W1[u * 4 + 1];
        const float w1v2 = W1[u * 4 + 2], w1v3 = W1[u * 4 + 3];
        const float w1h0 = W1[256], w1h1 = W1[257], w1h2 = W1[258], w1h3 = W1[259];
        const float b10 = b1[0], b11 = b1[1], b12 = b1[2], b13 = b1[3];
        const float wd = Wd[0], bdv = bd[0];

        float c1 = 0.f, h1 = 0.f, oval = 0.f;

        // reads its element's wave0-ring one step lagged: slot s&1 written in
        // the post-barrier phase of iter s (before B(s+1)), read after B(s+1),
        // rewritten in the post-barrier phase of iter s+2 -> race-free.
        #define L1STEP(s) { \
            const float hu = ringS0[eid][(s) & 1][u];  /* 4B stride: free */ \
            float p0 = hu * w1v0, p1 = hu * w1v1, p2 = hu * w1v2, p3 = hu * w1v3; \
            _Pragma("unroll") \
            for (int m = 1; m < 64; m <<= 1) { \
                p0 += __shfl_xor(p0, m, 64); \
                p1 += __shfl_xor(p1, m, 64); \
                p2 += __shfl_xor(p2, m, 64); \
                p3 += __shfl_xor(p3, m, 64); \
            } \
            const float z1i = p0 + fmaf(h1, w1h0, b10); \
            const float z1j = p1 + fmaf(h1, w1h1, b11); \
            const float z1f = p2 + fmaf(h1, w1h2, b12); \
            const float z1o = p3 + fmaf(h1, w1h3, b13); \
            c1 = fsigmoid(z1f + 1.0f) * c1 + fsigmoid(z1i) * ftanh(z1j); \
            h1 = fsigmoid(z1o) * ftanh(c1); \
            const float ov = fmaf(h1, wd, bdv); \
            if (((s) & 63) == u) oval = ov; \
            if (((s) & 63) == 63) outrow[((s) & ~63) + u] = oval; \
        }

        for (int t = 0; t < TT; ++t) {
            __syncthreads();  // B(t+1)
            if (t > 0) L1STEP(t - 1)
        }
        __syncthreads();  // B(TT+1) -- makes ring slot (TT-1)&1 visible
        L1STEP(TT - 1)
        #undef L1STEP
    }
}

extern "C" void kernel_launch(void* const* d_in, const int* in_sizes, int n_in,
                              void* d_out, int out_size, void* d_ws, size_t ws_size,
                              hipStream_t stream) {
    const float* x  = (const float*)d_in[0];
    const float* W0 = (const float*)d_in[1];
    const float* b0 = (const float*)d_in[2];
    const float* W1 = (const float*)d_in[3];
    const float* b1 = (const float*)d_in[4];
    const float* Wd = (const float*)d_in[5];
    const float* bd = (const float*)d_in[6];
    float* out = (float*)d_out;
    lstm_ts_kernel<<<NBLK, NTHR, 0, stream>>>(x, W0, b0, W1, b1, Wd, bd, out);
}

// Round 13
// 996.861 us; speedup vs baseline: 1.2769x; 1.2769x over previous
//
#include <hip/hip_runtime.h>
#include <math.h>

#define TT 2048
#define UU 64
#define BB 256
#define NTHR 192   // 3 waves: wave0 = gates(i,j), wave1 = gates(f,o), wave2 = consumer

typedef float v2f __attribute__((ext_vector_type(2)));
typedef float v4f __attribute__((ext_vector_type(4)));

// Fast activations on v_exp_f32 / v_rcp_f32 (~1e-7 abs err; threshold 3.45e-6;
// validated at absmax 9.5e-7 in rounds 0-11).
__device__ __forceinline__ float frcp(float x) { return __builtin_amdgcn_rcpf(x); }
__device__ __forceinline__ float fsigmoid(float x) { return frcp(1.0f + __expf(-x)); }
__device__ __forceinline__ float ftanh(float x) { return 1.0f - 2.0f * frcp(1.0f + __expf(2.0f * x)); }

// VOP3P op_sel splat-FMA (r10-validated). NOTE (r12): VOP3P cannot source
// AGPRs on gfx950 -- "a" constraints do not assemble. Weights must be in
// arch VGPRs; see amdgpu_num_vgpr below.
__device__ __forceinline__ void pkfma_ll(v2f& a, v2f h, v2f w) {
    asm("v_pk_fma_f32 %0, %1, %2, %0 op_sel:[0,0,0] op_sel_hi:[0,1,1]"
        : "+v"(a) : "v"(h), "v"(w));
}
__device__ __forceinline__ void pkfma_hh(v2f& a, v2f h, v2f w) {
    asm("v_pk_fma_f32 %0, %1, %2, %0 op_sel:[1,0,0] op_sel_hi:[1,1,1]"
        : "+v"(a) : "v"(h), "v"(w));
}

// ROUND-12 POST-MORTEM: VOP3P can't read AGPRs (compile fail), but the VALU
// arithmetic nailed r10's cost model: 430cy VALU/step/producer = 64 pkfma
// (128cy) + 128 v_accvgpr_read (256cy) + misc. The RA spills the 128 weight
// dwords to AGPRs (no scratch traffic, VGPR_Count=132) and pays a 2cy VALU
// read-back per dword per step. Root cause: the arch-VGPR ALLOCATION BUDGET
// stayed ~132 in every round -- waves_per_eu never raised it. THIS ROUND:
// r10 byte-for-byte + amdgpu_num_vgpr(256) -- the direct budget knob.
// 128 weights + ~40 working = 168 <= 256 -> weights stay in arch VGPRs, the
// 256cy/step AGPR tax disappears.
//
// Wave 0: lane u owns (i,j) columns {u, 64+u} of W0. Wave 1: (f,o) columns.
// Per step: matvec (16 uniform b128 h reads + 64 op_sel pkfma in 4 chains),
// write own (zA,zB) pair, ONE barrier, read other pair, redundant (c0,h)
// update -- bit-identical in both waves -- write own private plain-h ring.
// Wave 2 (consumer): after barrier t processes step t-1 from wave0's ring
// (written in (B(t),B(t+1)), rewritten after B(t+2): race-free): 4-value
// 64-lane shuffle reduce + layer-1 LSTM + dense, banks output, coalesced
// flush every 64 steps. All 3 waves execute exactly 1 + TT + 1 barriers.
__global__
__attribute__((amdgpu_flat_work_group_size(NTHR, NTHR)))
__attribute__((amdgpu_waves_per_eu(1, 1)))
__attribute__((amdgpu_num_vgpr(256)))
void lstm_ts_kernel(
    const float* __restrict__ x, const float* __restrict__ W0,
    const float* __restrict__ b0, const float* __restrict__ W1,
    const float* __restrict__ b1, const float* __restrict__ Wd,
    const float* __restrict__ bd, float* __restrict__ out)
{
    __shared__ __align__(16) float xbuf[TT];        // 8 KB
    __shared__ __align__(16) float ringS0[2][UU];   // wave0 plain-h ring
    __shared__ __align__(16) float ringS1[2][UU];   // wave1 private copy
    __shared__ __align__(16) v2f zb0[UU];           // (z_i, z_j) per unit
    __shared__ __align__(16) v2f zb1[UU];           // (z_f, z_o) per unit
    __shared__ float red[3];

    const int tid = threadIdx.x;
    const int wid = tid >> 6;
    const int u = tid & 63;
    const int b = blockIdx.x;
    const float* xrow = x + b * TT;
    float* outrow = out + b * TT;

    // ---- prologue: stage x, sum of squares over T (all 3 waves) ----
    float ss = 0.f;
    for (int i = tid; i < TT; i += NTHR) {
        float v = xrow[i];
        xbuf[i] = v;
        ss += v * v;
    }
    #pragma unroll
    for (int m = 1; m < 64; m <<= 1) ss += __shfl_xor(ss, m, 64);
    if (u == 0) red[wid] = ss;
    if (wid < 2) {  // h_{-1} = 0: step 0 reads slot 1
        (wid == 0 ? ringS0 : ringS1)[1][u] = 0.f;
    }
    __syncthreads();  // B0

    if (wid < 2) {
        // ============ PRODUCER wave 'wid': gate pair (i,j) or (f,o) ============
        const int go = wid * 128;  // column offset: 0 -> (i,j), 128 -> (f,o)
        const float sq = (red[0] + red[1]) + red[2];
        const float scale = 1.0f / sqrtf(fmaxf(sq, 1e-12f));  // precise, once

        // 64 named v2f = 128 weight VGPRs (now within the 256 arch budget).
        // WPk = (W[k][go+u], W[k][go+64+u]).
        #define DECLW(k) v2f WP##k; { const float* r_ = W0 + (1 + (k)) * 256 + go; \
            WP##k.x = r_[u]; WP##k.y = r_[64 + u]; } \
            asm volatile("" : "+v"(WP##k));
        DECLW(0)  DECLW(1)  DECLW(2)  DECLW(3)  DECLW(4)  DECLW(5)  DECLW(6)  DECLW(7)
        DECLW(8)  DECLW(9)  DECLW(10) DECLW(11) DECLW(12) DECLW(13) DECLW(14) DECLW(15)
        DECLW(16) DECLW(17) DECLW(18) DECLW(19) DECLW(20) DECLW(21) DECLW(22) DECLW(23)
        DECLW(24) DECLW(25) DECLW(26) DECLW(27) DECLW(28) DECLW(29) DECLW(30) DECLW(31)
        DECLW(32) DECLW(33) DECLW(34) DECLW(35) DECLW(36) DECLW(37) DECLW(38) DECLW(39)
        DECLW(40) DECLW(41) DECLW(42) DECLW(43) DECLW(44) DECLW(45) DECLW(46) DECLW(47)
        DECLW(48) DECLW(49) DECLW(50) DECLW(51) DECLW(52) DECLW(53) DECLW(54) DECLW(55)
        DECLW(56) DECLW(57) DECLW(58) DECLW(59) DECLW(60) DECLW(61) DECLW(62) DECLW(63)
        #undef DECLW

        const float wxa = W0[go + u] * scale;       // x-weight, gate a (i or f)
        const float wxb = W0[go + 64 + u] * scale;  // gate b (j or o)
        const float bca = b0[go + u], bcb = b0[go + 64 + u];

        float (*myring)[UU] = (wid == 0) ? ringS0 : ringS1;
        v2f* zbme = (wid == 0) ? zb0 : zb1;
        v2f* zbot = (wid == 0) ? zb1 : zb0;

        float c0 = 0.f;

        for (int t = 0; t < TT; ++t) {
            const float xr = xbuf[t];               // uniform broadcast
            const float* hs = myring[(t + 1) & 1];  // h_{t-1} (own private copy)

            // 4 chains x 16 deep; x-term folded into chain 0 (r10 bit-identical)
            v2f a0, a1 = 0.f, a2 = 0.f, a3 = 0.f;
            a0.x = fmaf(xr, wxa, bca); a0.y = fmaf(xr, wxb, bcb);

            // ONE uniform b128 read = h_{4m..4m+3} -> 4 op_sel pkfma
            #define MAC4(m, Wa, Wb, Wc, Wd_) { \
                v4f hv_ = *(const v4f*)(hs + 4 * (m)); \
                v2f h01_ = __builtin_shufflevector(hv_, hv_, 0, 1); \
                v2f h23_ = __builtin_shufflevector(hv_, hv_, 2, 3); \
                pkfma_ll(a0, h01_, Wa); pkfma_hh(a1, h01_, Wb); \
                pkfma_ll(a2, h23_, Wc); pkfma_hh(a3, h23_, Wd_); \
            }
            MAC4(0,  WP0,  WP1,  WP2,  WP3)
            MAC4(1,  WP4,  WP5,  WP6,  WP7)
            MAC4(2,  WP8,  WP9,  WP10, WP11)
            MAC4(3,  WP12, WP13, WP14, WP15)
            MAC4(4,  WP16, WP17, WP18, WP19)
            MAC4(5,  WP20, WP21, WP22, WP23)
            MAC4(6,  WP24, WP25, WP26, WP27)
            MAC4(7,  WP28, WP29, WP30, WP31)
            MAC4(8,  WP32, WP33, WP34, WP35)
            MAC4(9,  WP36, WP37, WP38, WP39)
            MAC4(10, WP40, WP41, WP42, WP43)
            MAC4(11, WP44, WP45, WP46, WP47)
            MAC4(12, WP48, WP49, WP50, WP51)
            MAC4(13, WP52, WP53, WP54, WP55)
            MAC4(14, WP56, WP57, WP58, WP59)
            MAC4(15, WP60, WP61, WP62, WP63)
            #undef MAC4

            const v2f zown = (a0 + a1) + (a2 + a3);  // own (zA, zB) pair
            zbme[u] = zown;                          // ds_write_b64
            __syncthreads();                         // B(t+1): pairs exchanged

            const v2f zoth = zbot[u];                // only the OTHER pair
            const v2f zij = (wid == 0) ? zown : zoth;
            const v2f zfo = (wid == 0) ? zoth : zown;

            // redundant unit update -- bit-identical in both producer waves
            c0 = fsigmoid(zfo.x + 1.0f) * c0 + fsigmoid(zij.x) * ftanh(zij.y);
            const float h = fsigmoid(zfo.y) * ftanh(c0);

            myring[t & 1][u] = h;  // plain h ring, b32 write
        }
        __syncthreads();  // B(TT+1)
    } else {
        // ================= CONSUMER: layer 1 + dense + store =================
        const float w1v0 = W1[u * 4 + 0], w1v1 = W1[u * 4 + 1];
        const float w1v2 = W1[u * 4 + 2], w1v3 = W1[u * 4 + 3];
        const float w1h0 = W1[256], w1h1 = W1[257], w1h2 = W1[258], w1h3 = W1[259];
        const float b10 = b1[0], b11 = b1[1], b12 = b1[2], b13 = b1[3];
        const float wd = Wd[0], bdv = bd[0];

        float c1 = 0.f, h1 = 0.f, oval = 0.f;

        // reads wave0's ring one step lagged: slot s&1 written in the
        // post-barrier phase of iter s, read after B(s+1), rewritten in the
        // post-barrier phase of iter s+2 (after B(s+2)) -> race-free.
        #define L1STEP(s) { \
            const float hu = ringS0[(s) & 1][u];  /* 4B stride: conflict-free */ \
            float p0 = hu * w1v0, p1 = hu * w1v1, p2 = hu * w1v2, p3 = hu * w1v3; \
            _Pragma("unroll") \
            for (int m = 1; m < 64; m <<= 1) { \
                p0 += __shfl_xor(p0, m, 64); \
                p1 += __shfl_xor(p1, m, 64); \
                p2 += __shfl_xor(p2, m, 64); \
                p3 += __shfl_xor(p3, m, 64); \
            } \
            const float z1i = p0 + fmaf(h1, w1h0, b10); \
            const float z1j = p1 + fmaf(h1, w1h1, b11); \
            const float z1f = p2 + fmaf(h1, w1h2, b12); \
            const float z1o = p3 + fmaf(h1, w1h3, b13); \
            c1 = fsigmoid(z1f + 1.0f) * c1 + fsigmoid(z1i) * ftanh(z1j); \
            h1 = fsigmoid(z1o) * ftanh(c1); \
            const float ov = fmaf(h1, wd, bdv); \
            if (((s) & 63) == u) oval = ov; \
            if (((s) & 63) == 63) outrow[((s) & ~63) + u] = oval; \
        }

        for (int t = 0; t < TT; ++t) {
            __syncthreads();  // B(t+1)
            if (t > 0) L1STEP(t - 1)
        }
        __syncthreads();  // B(TT+1) -- makes ring slot (TT-1)&1 visible
        L1STEP(TT - 1)
        #undef L1STEP
    }
}

extern "C" void kernel_launch(void* const* d_in, const int* in_sizes, int n_in,
                              void* d_out, int out_size, void* d_ws, size_t ws_size,
                              hipStream_t stream) {
    const float* x  = (const float*)d_in[0];
    const float* W0 = (const float*)d_in[1];
    const float* b0 = (const float*)d_in[2];
    const float* W1 = (const float*)d_in[3];
    const float* b1 = (const float*)d_in[4];
    const float* Wd = (const float*)d_in[5];
    const float* bd = (const float*)d_in[6];
    float* out = (float*)d_out;
    lstm_ts_kernel<<<BB, NTHR, 0, stream>>>(x, W0, b0, W1, b1, Wd, bd, out);
}

// Round 14
// 992.661 us; speedup vs baseline: 1.2823x; 1.0042x over previous
//
#include <hip/hip_runtime.h>
#include <math.h>

#define TT 2048
#define UU 64
#define BB 256
#define NTHR 192   // 3 waves: wave0 = gates(i,j), wave1 = gates(f,o), wave2 = consumer

typedef float v2f __attribute__((ext_vector_type(2)));
typedef float v4f __attribute__((ext_vector_type(4)));

// Fast activations on v_exp_f32 / v_rcp_f32 (~1e-7 abs err; threshold 3.45e-6;
// validated at absmax 9.5e-7 in rounds 0-13).
__device__ __forceinline__ float frcp(float x) { return __builtin_amdgcn_rcpf(x); }
__device__ __forceinline__ float fsigmoid(float x) { return frcp(1.0f + __expf(-x)); }
__device__ __forceinline__ float ftanh(float x) { return 1.0f - 2.0f * frcp(1.0f + __expf(2.0f * x)); }

// VOP3P op_sel splat-FMA (r10-validated). r12 ISA fact: VOP3P cannot source
// AGPRs on gfx950 -- weights MUST be in arch VGPRs to feed these.
__device__ __forceinline__ void pkfma_ll(v2f& a, v2f h, v2f w) {
    asm("v_pk_fma_f32 %0, %1, %2, %0 op_sel:[0,0,0] op_sel_hi:[0,1,1]"
        : "+v"(a) : "v"(h), "v"(w));
}
__device__ __forceinline__ void pkfma_hh(v2f& a, v2f h, v2f w) {
    asm("v_pk_fma_f32 %0, %1, %2, %0 op_sel:[1,0,0] op_sel_hi:[1,1,1]"
        : "+v"(a) : "v"(h), "v"(w));
}

// ROUND-13 POST-MORTEM: amdgpu_num_vgpr(256) is a CAP, not a floor -- inert
// (VGPR stayed 132). The RA homes the 128 weight dwords in AGPRs (unified
// file escape valve) and pays v_accvgpr_read copies on the VALU pipe every
// step (~up to 256cy of the measured 434cy VALU/step). THIS ROUND: CLOSE THE
// VALVE. 60 v4f dummies occupy 240/256 AGPRs, held by in-loop volatile "+a"
// pins (cannot be re-spilled mid-loop). Weights then have no AGPR home;
// live-range math (128 weights + ~50 working = ~178 < 256 arch VGPRs) says
// the greedy RA keeps them arch-resident with zero spill. In-loop "+v" pins
// on the weights additionally block a scratch home (tied in-out: zero
// instructions when already resident). Everything else r13 byte-for-byte.
//
// Wave 0: lane u owns (i,j) columns {u, 64+u} of W0. Wave 1: (f,o) columns.
// Per step: matvec (16 uniform b128 h reads + 64 op_sel pkfma in 4 chains),
// write own (zA,zB) pair, ONE barrier, read other pair, redundant (c0,h)
// update -- bit-identical in both waves -- write own private plain-h ring.
// Wave 2 (consumer): after barrier t processes step t-1 from wave0's ring
// (written in (B(t),B(t+1)), rewritten after B(t+2): race-free): 4-value
// 64-lane shuffle reduce + layer-1 LSTM + dense, banks output, coalesced
// flush every 64 steps. All 3 waves execute exactly 1 + TT + 1 barriers.
__global__
__attribute__((amdgpu_flat_work_group_size(NTHR, NTHR)))
__attribute__((amdgpu_waves_per_eu(1, 1)))
__attribute__((amdgpu_num_vgpr(256)))
void lstm_ts_kernel(
    const float* __restrict__ x, const float* __restrict__ W0,
    const float* __restrict__ b0, const float* __restrict__ W1,
    const float* __restrict__ b1, const float* __restrict__ Wd,
    const float* __restrict__ bd, float* __restrict__ out)
{
    __shared__ __align__(16) float xbuf[TT];        // 8 KB
    __shared__ __align__(16) float ringS0[2][UU];   // wave0 plain-h ring
    __shared__ __align__(16) float ringS1[2][UU];   // wave1 private copy
    __shared__ __align__(16) v2f zb0[UU];           // (z_i, z_j) per unit
    __shared__ __align__(16) v2f zb1[UU];           // (z_f, z_o) per unit
    __shared__ float red[3];

    const int tid = threadIdx.x;
    const int wid = tid >> 6;
    const int u = tid & 63;
    const int b = blockIdx.x;
    const float* xrow = x + b * TT;
    float* outrow = out + b * TT;

    // ---- prologue: stage x, sum of squares over T (all 3 waves) ----
    float ss = 0.f;
    for (int i = tid; i < TT; i += NTHR) {
        float v = xrow[i];
        xbuf[i] = v;
        ss += v * v;
    }
    #pragma unroll
    for (int m = 1; m < 64; m <<= 1) ss += __shfl_xor(ss, m, 64);
    if (u == 0) red[wid] = ss;
    if (wid < 2) {  // h_{-1} = 0: step 0 reads slot 1
        (wid == 0 ? ringS0 : ringS1)[1][u] = 0.f;
    }
    __syncthreads();  // B0

    if (wid < 2) {
        // ============ PRODUCER wave 'wid': gate pair (i,j) or (f,o) ============
        const int go = wid * 128;  // column offset: 0 -> (i,j), 128 -> (f,o)
        const float sq = (red[0] + red[1]) + red[2];
        const float scale = 1.0f / sqrtf(fmaxf(sq, 1e-12f));  // precise, once

        // AGPR blockers: 60 v4f = 240 AGPRs occupied for the whole loop.
        #define DECLA(k) v4f AD##k = {0.f, 0.f, 0.f, 0.f}; \
            asm volatile("" : "+a"(AD##k));
        DECLA(0)  DECLA(1)  DECLA(2)  DECLA(3)  DECLA(4)  DECLA(5)
        DECLA(6)  DECLA(7)  DECLA(8)  DECLA(9)  DECLA(10) DECLA(11)
        DECLA(12) DECLA(13) DECLA(14) DECLA(15) DECLA(16) DECLA(17)
        DECLA(18) DECLA(19) DECLA(20) DECLA(21) DECLA(22) DECLA(23)
        DECLA(24) DECLA(25) DECLA(26) DECLA(27) DECLA(28) DECLA(29)
        DECLA(30) DECLA(31) DECLA(32) DECLA(33) DECLA(34) DECLA(35)
        DECLA(36) DECLA(37) DECLA(38) DECLA(39) DECLA(40) DECLA(41)
        DECLA(42) DECLA(43) DECLA(44) DECLA(45) DECLA(46) DECLA(47)
        DECLA(48) DECLA(49) DECLA(50) DECLA(51) DECLA(52) DECLA(53)
        DECLA(54) DECLA(55) DECLA(56) DECLA(57) DECLA(58) DECLA(59)
        #undef DECLA

        // 64 named v2f = 128 weight VGPRs. WPk = (W[k][go+u], W[k][go+64+u]).
        #define DECLW(k) v2f WP##k; { const float* r_ = W0 + (1 + (k)) * 256 + go; \
            WP##k.x = r_[u]; WP##k.y = r_[64 + u]; } \
            asm volatile("" : "+v"(WP##k));
        DECLW(0)  DECLW(1)  DECLW(2)  DECLW(3)  DECLW(4)  DECLW(5)  DECLW(6)  DECLW(7)
        DECLW(8)  DECLW(9)  DECLW(10) DECLW(11) DECLW(12) DECLW(13) DECLW(14) DECLW(15)
        DECLW(16) DECLW(17) DECLW(18) DECLW(19) DECLW(20) DECLW(21) DECLW(22) DECLW(23)
        DECLW(24) DECLW(25) DECLW(26) DECLW(27) DECLW(28) DECLW(29) DECLW(30) DECLW(31)
        DECLW(32) DECLW(33) DECLW(34) DECLW(35) DECLW(36) DECLW(37) DECLW(38) DECLW(39)
        DECLW(40) DECLW(41) DECLW(42) DECLW(43) DECLW(44) DECLW(45) DECLW(46) DECLW(47)
        DECLW(48) DECLW(49) DECLW(50) DECLW(51) DECLW(52) DECLW(53) DECLW(54) DECLW(55)
        DECLW(56) DECLW(57) DECLW(58) DECLW(59) DECLW(60) DECLW(61) DECLW(62) DECLW(63)
        #undef DECLW

        const float wxa = W0[go + u] * scale;       // x-weight, gate a (i or f)
        const float wxb = W0[go + 64 + u] * scale;  // gate b (j or o)
        const float bca = b0[go + u], bcb = b0[go + 64 + u];

        float (*myring)[UU] = (wid == 0) ? ringS0 : ringS1;
        v2f* zbme = (wid == 0) ? zb0 : zb1;
        v2f* zbot = (wid == 0) ? zb1 : zb0;

        float c0 = 0.f;

        for (int t = 0; t < TT; ++t) {
            // in-loop pins: dummies stay in AGPRs (valve closed), weights
            // stay in arch VGPRs (no scratch home). Zero emitted instructions.
            #define PINA(k) asm volatile("" : "+a"(AD##k));
            PINA(0)  PINA(1)  PINA(2)  PINA(3)  PINA(4)  PINA(5)
            PINA(6)  PINA(7)  PINA(8)  PINA(9)  PINA(10) PINA(11)
            PINA(12) PINA(13) PINA(14) PINA(15) PINA(16) PINA(17)
            PINA(18) PINA(19) PINA(20) PINA(21) PINA(22) PINA(23)
            PINA(24) PINA(25) PINA(26) PINA(27) PINA(28) PINA(29)
            PINA(30) PINA(31) PINA(32) PINA(33) PINA(34) PINA(35)
            PINA(36) PINA(37) PINA(38) PINA(39) PINA(40) PINA(41)
            PINA(42) PINA(43) PINA(44) PINA(45) PINA(46) PINA(47)
            PINA(48) PINA(49) PINA(50) PINA(51) PINA(52) PINA(53)
            PINA(54) PINA(55) PINA(56) PINA(57) PINA(58) PINA(59)
            #undef PINA
            #define PINW(k) asm volatile("" : "+v"(WP##k));
            PINW(0)  PINW(1)  PINW(2)  PINW(3)  PINW(4)  PINW(5)  PINW(6)  PINW(7)
            PINW(8)  PINW(9)  PINW(10) PINW(11) PINW(12) PINW(13) PINW(14) PINW(15)
            PINW(16) PINW(17) PINW(18) PINW(19) PINW(20) PINW(21) PINW(22) PINW(23)
            PINW(24) PINW(25) PINW(26) PINW(27) PINW(28) PINW(29) PINW(30) PINW(31)
            PINW(32) PINW(33) PINW(34) PINW(35) PINW(36) PINW(37) PINW(38) PINW(39)
            PINW(40) PINW(41) PINW(42) PINW(43) PINW(44) PINW(45) PINW(46) PINW(47)
            PINW(48) PINW(49) PINW(50) PINW(51) PINW(52) PINW(53) PINW(54) PINW(55)
            PINW(56) PINW(57) PINW(58) PINW(59) PINW(60) PINW(61) PINW(62) PINW(63)
            #undef PINW

            const float xr = xbuf[t];               // uniform broadcast
            const float* hs = myring[(t + 1) & 1];  // h_{t-1} (own private copy)

            // 4 chains x 16 deep; x-term folded into chain 0 (r10 bit-identical)
            v2f a0, a1 = 0.f, a2 = 0.f, a3 = 0.f;
            a0.x = fmaf(xr, wxa, bca); a0.y = fmaf(xr, wxb, bcb);

            // ONE uniform b128 read = h_{4m..4m+3} -> 4 op_sel pkfma
            #define MAC4(m, Wa, Wb, Wc, Wd_) { \
                v4f hv_ = *(const v4f*)(hs + 4 * (m)); \
                v2f h01_ = __builtin_shufflevector(hv_, hv_, 0, 1); \
                v2f h23_ = __builtin_shufflevector(hv_, hv_, 2, 3); \
                pkfma_ll(a0, h01_, Wa); pkfma_hh(a1, h01_, Wb); \
                pkfma_ll(a2, h23_, Wc); pkfma_hh(a3, h23_, Wd_); \
            }
            MAC4(0,  WP0,  WP1,  WP2,  WP3)
            MAC4(1,  WP4,  WP5,  WP6,  WP7)
            MAC4(2,  WP8,  WP9,  WP10, WP11)
            MAC4(3,  WP12, WP13, WP14, WP15)
            MAC4(4,  WP16, WP17, WP18, WP19)
            MAC4(5,  WP20, WP21, WP22, WP23)
            MAC4(6,  WP24, WP25, WP26, WP27)
            MAC4(7,  WP28, WP29, WP30, WP31)
            MAC4(8,  WP32, WP33, WP34, WP35)
            MAC4(9,  WP36, WP37, WP38, WP39)
            MAC4(10, WP40, WP41, WP42, WP43)
            MAC4(11, WP44, WP45, WP46, WP47)
            MAC4(12, WP48, WP49, WP50, WP51)
            MAC4(13, WP52, WP53, WP54, WP55)
            MAC4(14, WP56, WP57, WP58, WP59)
            MAC4(15, WP60, WP61, WP62, WP63)
            #undef MAC4

            const v2f zown = (a0 + a1) + (a2 + a3);  // own (zA, zB) pair
            zbme[u] = zown;                          // ds_write_b64
            __syncthreads();                         // B(t+1): pairs exchanged

            const v2f zoth = zbot[u];                // only the OTHER pair
            const v2f zij = (wid == 0) ? zown : zoth;
            const v2f zfo = (wid == 0) ? zoth : zown;

            // redundant unit update -- bit-identical in both producer waves
            c0 = fsigmoid(zfo.x + 1.0f) * c0 + fsigmoid(zij.x) * ftanh(zij.y);
            const float h = fsigmoid(zfo.y) * ftanh(c0);

            myring[t & 1][u] = h;  // plain h ring, b32 write
        }
        __syncthreads();  // B(TT+1)
    } else {
        // ================= CONSUMER: layer 1 + dense + store =================
        const float w1v0 = W1[u * 4 + 0], w1v1 = W1[u * 4 + 1];
        const float w1v2 = W1[u * 4 + 2], w1v3 = W1[u * 4 + 3];
        const float w1h0 = W1[256], w1h1 = W1[257], w1h2 = W1[258], w1h3 = W1[259];
        const float b10 = b1[0], b11 = b1[1], b12 = b1[2], b13 = b1[3];
        const float wd = Wd[0], bdv = bd[0];

        float c1 = 0.f, h1 = 0.f, oval = 0.f;

        // reads wave0's ring one step lagged: slot s&1 written in the
        // post-barrier phase of iter s, read after B(s+1), rewritten in the
        // post-barrier phase of iter s+2 (after B(s+2)) -> race-free.
        #define L1STEP(s) { \
            const float hu = ringS0[(s) & 1][u];  /* 4B stride: conflict-free */ \
            float p0 = hu * w1v0, p1 = hu * w1v1, p2 = hu * w1v2, p3 = hu * w1v3; \
            _Pragma("unroll") \
            for (int m = 1; m < 64; m <<= 1) { \
                p0 += __shfl_xor(p0, m, 64); \
                p1 += __shfl_xor(p1, m, 64); \
                p2 += __shfl_xor(p2, m, 64); \
                p3 += __shfl_xor(p3, m, 64); \
            } \
            const float z1i = p0 + fmaf(h1, w1h0, b10); \
            const float z1j = p1 + fmaf(h1, w1h1, b11); \
            const float z1f = p2 + fmaf(h1, w1h2, b12); \
            const float z1o = p3 + fmaf(h1, w1h3, b13); \
            c1 = fsigmoid(z1f + 1.0f) * c1 + fsigmoid(z1i) * ftanh(z1j); \
            h1 = fsigmoid(z1o) * ftanh(c1); \
            const float ov = fmaf(h1, wd, bdv); \
            if (((s) & 63) == u) oval = ov; \
            if (((s) & 63) == 63) outrow[((s) & ~63) + u] = oval; \
        }

        for (int t = 0; t < TT; ++t) {
            __syncthreads();  // B(t+1)
            if (t > 0) L1STEP(t - 1)
        }
        __syncthreads();  // B(TT+1) -- makes ring slot (TT-1)&1 visible
        L1STEP(TT - 1)
        #undef L1STEP
    }
}

extern "C" void kernel_launch(void* const* d_in, const int* in_sizes, int n_in,
                              void* d_out, int out_size, void* d_ws, size_t ws_size,
                              hipStream_t stream) {
    const float* x  = (const float*)d_in[0];
    const float* W0 = (const float*)d_in[1];
    const float* b0 = (const float*)d_in[2];
    const float* W1 = (const float*)d_in[3];
    const float* b1 = (const float*)d_in[4];
    const float* Wd = (const float*)d_in[5];
    const float* bd = (const float*)d_in[6];
    float* out = (float*)d_out;
    lstm_ts_kernel<<<BB, NTHR, 0, stream>>>(x, W0, b0, W1, b1, Wd, bd, out);
}

// Round 16
// 959.371 us; speedup vs baseline: 1.3268x; 1.0347x over previous
//
#include <hip/hip_runtime.h>
#include <math.h>

#define TT 2048
#define UU 64
#define BB 256
#define NTHR 192   // 3 waves: wave0 = k:0..31 (all gates), wave1 = k:32..63, wave2 = consumer

typedef float v2f __attribute__((ext_vector_type(2)));
typedef float v4f __attribute__((ext_vector_type(4)));

// Fast activations on v_exp_f32 / v_rcp_f32 (~1e-7 abs err; threshold 3.45e-6;
// validated at absmax 9.5e-7 in rounds 0-14).
__device__ __forceinline__ float frcp(float x) { return __builtin_amdgcn_rcpf(x); }
__device__ __forceinline__ float fsigmoid(float x) { return frcp(1.0f + __expf(-x)); }
__device__ __forceinline__ float ftanh(float x) { return 1.0f - 2.0f * frcp(1.0f + __expf(2.0f * x)); }

// VOP3P op_sel splat-FMA (r10-validated): both result halves consume the SAME
// 32-bit half of h -- no (h,h) splat is ever materialized.
__device__ __forceinline__ void pkfma_ll(v2f& a, v2f h, v2f w) {
    asm("v_pk_fma_f32 %0, %1, %2, %0 op_sel:[0,0,0] op_sel_hi:[0,1,1]"
        : "+v"(a) : "v"(h), "v"(w));
}
__device__ __forceinline__ void pkfma_hh(v2f& a, v2f h, v2f w) {
    asm("v_pk_fma_f32 %0, %1, %2, %0 op_sel:[1,0,0] op_sel_hi:[1,1,1]"
        : "+v"(a) : "v"(h), "v"(w));
}

// ROUND-14 POST-MORTEM: weights in arch VGPRs (228, blockers) vs AGPR-copies
// (132) = IDENTICAL time -> weight residency was never on the critical path.
// The step is a serial latency chain; the only cuttable segment left is the
// DS-pipe issue + in-order drain. THIS ROUND (resubmitted; r15 was an infra
// failure, kernel never ran): K-SPLIT producers.
// Wave w accumulates h-half k in [32w, 32w+32) for ALL FOUR gates of unit u
// (32 rows x 4 cols = 128 weight VGPRs, same footprint):
//   * ring reads per wave: 8 uniform b128 (was 16) -> DS ops/step 19 -> 11.
//   * z-exchange carries 4 partial sums (one b128 each way); after it, each
//     lane holds all four z's -> no gate exchange, no wid-selects.
//   * zpart is double-buffered by t&1 -> the r10 timing-margin overwrite
//     window is structurally closed.
//   * x-row + biases folded into wave0's chain inits (wave1 inits exact 0).
// Per step: [MAC: 8 uniform b128 + 64 pkfma, 4 chains x 16] -> partial b128
// write -> ONE barrier -> partner partial b128 read -> 4 adds -> acts
// (redundant in both waves, bit-identical) -> h -> private ring b32 write.
// Wave 2 (consumer): r10's proven 1-step-lag protocol on wave0's ring:
// 4-value 64-lane shuffle reduce + layer-1 LSTM + dense, coalesced flush
// every 64 steps. All 3 waves execute exactly 1 + TT + 1 barriers.
__global__
__attribute__((amdgpu_flat_work_group_size(NTHR, NTHR)))
__attribute__((amdgpu_waves_per_eu(1, 1)))
void lstm_ts_kernel(
    const float* __restrict__ x, const float* __restrict__ W0,
    const float* __restrict__ b0, const float* __restrict__ W1,
    const float* __restrict__ b1, const float* __restrict__ Wd,
    const float* __restrict__ bd, float* __restrict__ out)
{
    __shared__ __align__(16) float xbuf[TT];          // 8 KB
    __shared__ __align__(16) float ringP[2][2][UU];   // private full-h rings, 1 KB
    __shared__ __align__(16) v4f  zpart[2][2][UU];    // [t&1][wid][u] partials, 4 KB
    __shared__ float red[3];

    const int tid = threadIdx.x;
    const int wid = tid >> 6;
    const int u = tid & 63;
    const int b = blockIdx.x;
    const float* xrow = x + b * TT;
    float* outrow = out + b * TT;

    // ---- prologue: stage x, sum of squares over T (all 3 waves) ----
    float ss = 0.f;
    for (int i = tid; i < TT; i += NTHR) {
        float v = xrow[i];
        xbuf[i] = v;
        ss += v * v;
    }
    #pragma unroll
    for (int m = 1; m < 64; m <<= 1) ss += __shfl_xor(ss, m, 64);
    if (u == 0) red[wid] = ss;
    if (wid < 2) ringP[wid][1][u] = 0.f;  // h_{-1}=0: step 0 reads slot 1
    __syncthreads();  // B0

    if (wid < 2) {
        // ========= PRODUCER wave 'wid': k-half [32*wid, 32*wid+32) =========
        const int koff = 32 * wid;
        const float sq = (red[0] + red[1]) + red[2];
        const float scale = 1.0f / sqrtf(fmaxf(sq, 1e-12f));  // precise, once

        // 64 named v2f = 128 weight VGPRs. For local k (global row 1+koff+k):
        // WIk = (Wi[k][u], Wj[k][u]); WFk = (Wf[k][u], Wo[k][u]).
        #define DECLW(k) v2f WI##k, WF##k; { \
            const float* r_ = W0 + (1 + koff + (k)) * 256; \
            WI##k.x = r_[u];       WI##k.y = r_[64 + u]; \
            WF##k.x = r_[128 + u]; WF##k.y = r_[192 + u]; } \
            asm volatile("" : "+v"(WI##k)); asm volatile("" : "+v"(WF##k));
        DECLW(0)  DECLW(1)  DECLW(2)  DECLW(3)  DECLW(4)  DECLW(5)  DECLW(6)  DECLW(7)
        DECLW(8)  DECLW(9)  DECLW(10) DECLW(11) DECLW(12) DECLW(13) DECLW(14) DECLW(15)
        DECLW(16) DECLW(17) DECLW(18) DECLW(19) DECLW(20) DECLW(21) DECLW(22) DECLW(23)
        DECLW(24) DECLW(25) DECLW(26) DECLW(27) DECLW(28) DECLW(29) DECLW(30) DECLW(31)
        #undef DECLW

        // x-row + biases: carried by wave0 only (wave1 chains start at exact 0)
        const float sel = (wid == 0) ? 1.f : 0.f;
        const float wxi = W0[u] * scale * sel,       wxj = W0[64 + u] * scale * sel;
        const float wxf = W0[128 + u] * scale * sel, wxo = W0[192 + u] * scale * sel;
        const float bci = b0[u] * sel,       bcj = b0[64 + u] * sel;
        const float bcf = b0[128 + u] * sel, bco = b0[192 + u] * sel;

        float c0 = 0.f;

        for (int t = 0; t < TT; ++t) {
            const float xr = xbuf[t];                            // uniform
            const float* hs = &ringP[wid][(t + 1) & 1][koff];    // own K-half

            // 4 chains x 16 deep; x/bias folded into chain 0 (wave0)
            v2f ai0, ai1 = 0.f, af0, af1 = 0.f;
            ai0.x = fmaf(xr, wxi, bci); ai0.y = fmaf(xr, wxj, bcj);
            af0.x = fmaf(xr, wxf, bcf); af0.y = fmaf(xr, wxo, bco);

            // one uniform b128 read = h_{koff+4m..4m+3} -> 8 op_sel pkfma
            #define MACR(m, A, B, C, D, E, F, G, H) { \
                v4f hv_ = *(const v4f*)(hs + 4 * (m)); \
                v2f h01_ = __builtin_shufflevector(hv_, hv_, 0, 1); \
                v2f h23_ = __builtin_shufflevector(hv_, hv_, 2, 3); \
                pkfma_ll(ai0, h01_, A); pkfma_ll(af0, h01_, E); \
                pkfma_hh(ai1, h01_, B); pkfma_hh(af1, h01_, F); \
                pkfma_ll(ai0, h23_, C); pkfma_ll(af0, h23_, G); \
                pkfma_hh(ai1, h23_, D); pkfma_hh(af1, h23_, H); \
            }
            MACR(0, WI0,  WI1,  WI2,  WI3,  WF0,  WF1,  WF2,  WF3)
            MACR(1, WI4,  WI5,  WI6,  WI7,  WF4,  WF5,  WF6,  WF7)
            MACR(2, WI8,  WI9,  WI10, WI11, WF8,  WF9,  WF10, WF11)
            MACR(3, WI12, WI13, WI14, WI15, WF12, WF13, WF14, WF15)
            MACR(4, WI16, WI17, WI18, WI19, WF16, WF17, WF18, WF19)
            MACR(5, WI20, WI21, WI22, WI23, WF20, WF21, WF22, WF23)
            MACR(6, WI24, WI25, WI26, WI27, WF24, WF25, WF26, WF27)
            MACR(7, WI28, WI29, WI30, WI31, WF28, WF29, WF30, WF31)
            #undef MACR

            const v2f pij = ai0 + ai1;   // own-half partial (z_i, z_j)
            const v2f pfo = af0 + af1;   // own-half partial (z_f, z_o)
            v4f zp; zp.x = pij.x; zp.y = pij.y; zp.z = pfo.x; zp.w = pfo.y;
            zpart[t & 1][wid][u] = zp;   // ds_write_b128
            __syncthreads();             // B(t+1): partials exchanged

            const v4f zo4 = zpart[t & 1][1 - wid][u];  // partner's partial
            const float zi = pij.x + zo4.x;
            const float zj = pij.y + zo4.y;
            const float zf = pfo.x + zo4.z;
            const float zo = pfo.y + zo4.w;

            // unit update -- bit-identical in both producer waves
            c0 = fsigmoid(zf + 1.0f) * c0 + fsigmoid(zi) * ftanh(zj);
            const float h = fsigmoid(zo) * ftanh(c0);

            ringP[wid][t & 1][u] = h;    // private full-h ring, b32 write
        }
        __syncthreads();  // B(TT+1)
    } else {
        // ================= CONSUMER: layer 1 + dense + store =================
        const float w1v0 = W1[u * 4 + 0], w1v1 = W1[u * 4 + 1];
        const float w1v2 = W1[u * 4 + 2], w1v3 = W1[u * 4 + 3];
        const float w1h0 = W1[256], w1h1 = W1[257], w1h2 = W1[258], w1h3 = W1[259];
        const float b10 = b1[0], b11 = b1[1], b12 = b1[2], b13 = b1[3];
        const float wd = Wd[0], bdv = bd[0];

        float c1 = 0.f, h1 = 0.f, oval = 0.f;

        // reads wave0's ring one step lagged: slot s&1 written by wave0 in
        // its post-B(s+1) segment; consumer reads after B(s+2) (requires
        // wave0's arrival -> after the write); slot rewritten only after
        // B(s+3) (requires the consumer's arrival -> after the read).
        #define L1STEP(s) { \
            const float hu = ringP[0][(s) & 1][u];  /* 4B stride: conflict-free */ \
            float p0 = hu * w1v0, p1 = hu * w1v1, p2 = hu * w1v2, p3 = hu * w1v3; \
            _Pragma("unroll") \
            for (int m = 1; m < 64; m <<= 1) { \
                p0 += __shfl_xor(p0, m, 64); \
                p1 += __shfl_xor(p1, m, 64); \
                p2 += __shfl_xor(p2, m, 64); \
                p3 += __shfl_xor(p3, m, 64); \
            } \
            const float z1i = p0 + fmaf(h1, w1h0, b10); \
            const float z1j = p1 + fmaf(h1, w1h1, b11); \
            const float z1f = p2 + fmaf(h1, w1h2, b12); \
            const float z1o = p3 + fmaf(h1, w1h3, b13); \
            c1 = fsigmoid(z1f + 1.0f) * c1 + fsigmoid(z1i) * ftanh(z1j); \
            h1 = fsigmoid(z1o) * ftanh(c1); \
            const float ov = fmaf(h1, wd, bdv); \
            if (((s) & 63) == u) oval = ov; \
            if (((s) & 63) == 63) outrow[((s) & ~63) + u] = oval; \
        }

        for (int t = 0; t < TT; ++t) {
            __syncthreads();  // B(t+1)
            if (t > 0) L1STEP(t - 1)
        }
        __syncthreads();  // B(TT+1) -- makes ring slot (TT-1)&1 visible
        L1STEP(TT - 1)
        #undef L1STEP
    }
}

extern "C" void kernel_launch(void* const* d_in, const int* in_sizes, int n_in,
                              void* d_out, int out_size, void* d_ws, size_t ws_size,
                              hipStream_t stream) {
    const float* x  = (const float*)d_in[0];
    const float* W0 = (const float*)d_in[1];
    const float* b0 = (const float*)d_in[2];
    const float* W1 = (const float*)d_in[3];
    const float* b1 = (const float*)d_in[4];
    const float* Wd = (const float*)d_in[5];
    const float* bd = (const float*)d_in[6];
    float* out = (float*)d_out;
    lstm_ts_kernel<<<BB, NTHR, 0, stream>>>(x, W0, b0, W1, b1, Wd, bd, out);
}